// Round 1
// baseline (1429.996 us; speedup 1.0000x reference)
//
#include <hip/hip_runtime.h>
#include <cstdint>
#include <cstddef>

#define NN 50000
#define EE 800000
#define CAP 64
#define EPS_BN 1e-5f

// ---------------- graph preprocessing ----------------

__global__ void k_outdeg(const int* __restrict__ row, int* __restrict__ outdeg){
  int e = blockIdx.x * blockDim.x + threadIdx.x;
  if (e < EE) atomicAdd(&outdeg[row[e]], 1);
}

__global__ void k_fill(const int* __restrict__ row, const int* __restrict__ col,
                       const int* __restrict__ outdeg,
                       int* __restrict__ incnt, int* __restrict__ bsrc,
                       float* __restrict__ bnorm){
  int e = blockIdx.x * blockDim.x + threadIdx.x;
  if (e >= EE) return;
  int r = row[e], c = col[e];
  int j = atomicAdd(&incnt[c], 1);
  if (j < CAP){
    bsrc[(size_t)c * CAP + j]  = r;
    bnorm[(size_t)c * CAP + j] = 1.0f / fmaxf((float)outdeg[r], 1.0f);
  }
}

// ---------------- aggregations (wave per node, lane = feature) ----------------

__global__ void k_agg_mean(const float* __restrict__ hin, float* __restrict__ out,
                           const int* __restrict__ bsrc, const int* __restrict__ incnt){
  int wid  = (int)((blockIdx.x * blockDim.x + threadIdx.x) >> 6);
  int lane = threadIdx.x & 63;
  if (wid >= NN) return;
  int cnt  = incnt[wid];
  int cntb = min(cnt, CAP);
  const int* b = bsrc + (size_t)wid * CAP;
  int s_l = (lane < cntb) ? b[lane] : 0;
  float acc = 0.f;
  int j = 0;
  for (; j + 4 <= cntb; j += 4){
    int s0 = __shfl(s_l, j), s1 = __shfl(s_l, j+1), s2 = __shfl(s_l, j+2), s3 = __shfl(s_l, j+3);
    float a0 = hin[(size_t)s0*64+lane], a1 = hin[(size_t)s1*64+lane];
    float a2 = hin[(size_t)s2*64+lane], a3 = hin[(size_t)s3*64+lane];
    acc += a0 + a1 + a2 + a3;
  }
  for (; j < cntb; ++j) acc += hin[(size_t)__shfl(s_l, j)*64 + lane];
  out[(size_t)wid*64 + lane] = acc / fmaxf((float)cnt, 1.0f);
}

__global__ void k_agg_path(const float* __restrict__ pin, float* __restrict__ pout,
                           const int* __restrict__ bsrc, const float* __restrict__ bnorm,
                           const int* __restrict__ incnt){
  int wid  = (int)((blockIdx.x * blockDim.x + threadIdx.x) >> 6);
  int lane = threadIdx.x & 63;
  if (wid >= NN) return;
  int cnt = min(incnt[wid], CAP);
  const int*   b  = bsrc  + (size_t)wid * CAP;
  const float* nr = bnorm + (size_t)wid * CAP;
  int   s_l = (lane < cnt) ? b[lane]  : 0;
  float n_l = (lane < cnt) ? nr[lane] : 0.f;
  float acc = 0.f;
  int j = 0;
  for (; j + 4 <= cnt; j += 4){
    int s0 = __shfl(s_l, j), s1 = __shfl(s_l, j+1), s2 = __shfl(s_l, j+2), s3 = __shfl(s_l, j+3);
    float w0 = __shfl(n_l, j), w1 = __shfl(n_l, j+1), w2 = __shfl(n_l, j+2), w3 = __shfl(n_l, j+3);
    acc = fmaf(w0, pin[(size_t)s0*64+lane], acc);
    acc = fmaf(w1, pin[(size_t)s1*64+lane], acc);
    acc = fmaf(w2, pin[(size_t)s2*64+lane], acc);
    acc = fmaf(w3, pin[(size_t)s3*64+lane], acc);
  }
  for (; j < cnt; ++j)
    acc = fmaf(__shfl(n_l, j), pin[(size_t)__shfl(s_l, j)*64 + lane], acc);
  pout[(size_t)wid*64 + lane] = acc;
}

// ---------------- dense ops ----------------

// out = X @ W (64x64) + b      (wave per node, lane = out feature)
__global__ void __launch_bounds__(256) k_gemm64(const float* __restrict__ X,
                                                const float* __restrict__ W,
                                                const float* __restrict__ bias,
                                                float* __restrict__ out){
  __shared__ float sW[4096];
  __shared__ float sb[64];
  for (int i = threadIdx.x; i < 4096; i += 256) sW[i] = W[i];
  if (threadIdx.x < 64) sb[threadIdx.x] = bias[threadIdx.x];
  __syncthreads();
  int lane = threadIdx.x & 63, wib = threadIdx.x >> 6;
  int stride = (blockDim.x >> 6) * gridDim.x;
  for (int n = blockIdx.x * (blockDim.x >> 6) + wib; n < NN; n += stride){
    float xv  = X[(size_t)n*64 + lane];
    float acc = sb[lane];
    #pragma unroll
    for (int k = 0; k < 64; ++k) acc = fmaf(__shfl(xv, k), sW[k*64 + lane], acc);
    out[(size_t)n*64 + lane] = acc;
  }
}

// h_out = relu(bn(mean@Wl + bl + h@Wr)) + h
__global__ void __launch_bounds__(256) k_sage(const float* __restrict__ h,
                                              const float* __restrict__ mean,
                                              const float* __restrict__ Wl,
                                              const float* __restrict__ bl,
                                              const float* __restrict__ Wr,
                                              const float* __restrict__ g,
                                              const float* __restrict__ be,
                                              const float* __restrict__ m,
                                              const float* __restrict__ var_,
                                              float* __restrict__ hout){
  __shared__ float sWl[4096], sWr[4096];
  __shared__ float ssc[64], ssh[64], sbl[64];
  for (int i = threadIdx.x; i < 4096; i += 256){ sWl[i] = Wl[i]; sWr[i] = Wr[i]; }
  if (threadIdx.x < 64){
    int f = threadIdx.x;
    float sc = g[f] * rsqrtf(var_[f] + EPS_BN);
    ssc[f] = sc; ssh[f] = be[f] - m[f] * sc; sbl[f] = bl[f];
  }
  __syncthreads();
  int lane = threadIdx.x & 63, wib = threadIdx.x >> 6;
  int stride = (blockDim.x >> 6) * gridDim.x;
  for (int n = blockIdx.x * (blockDim.x >> 6) + wib; n < NN; n += stride){
    float hv = h[(size_t)n*64 + lane];
    float mv = mean[(size_t)n*64 + lane];
    float acc = sbl[lane];
    #pragma unroll
    for (int k = 0; k < 64; ++k){
      acc = fmaf(__shfl(mv, k), sWl[k*64 + lane], acc);
      acc = fmaf(__shfl(hv, k), sWr[k*64 + lane], acc);
    }
    float t = fmaf(acc, ssc[lane], ssh[lane]);
    hout[(size_t)n*64 + lane] = fmaxf(t, 0.f) + hv;
  }
}

// [Y|R] = pieces(384) @ [vW_l|vW_r];  R gets +vb_l.   32 nodes per block.
__global__ void __launch_bounds__(256) k_gemm_YR(
    const float* __restrict__ x0, const float* __restrict__ x1, const float* __restrict__ x2,
    const float* __restrict__ x3, const float* __restrict__ x4, const float* __restrict__ x5,
    const float* __restrict__ WL, const float* __restrict__ WR, const float* __restrict__ vbl,
    float* __restrict__ Y, float* __restrict__ R){
  __shared__ float sWL[4096], sWR[4096];
  const float* X[6] = {x0, x1, x2, x3, x4, x5};
  int lane = threadIdx.x & 63, wib = threadIdx.x >> 6;
  int base = blockIdx.x * 32 + wib * 8;
  float accY[8] = {0,0,0,0,0,0,0,0};
  float accR[8] = {0,0,0,0,0,0,0,0};
  #pragma unroll
  for (int p = 0; p < 6; ++p){
    __syncthreads();
    for (int i = threadIdx.x; i < 4096; i += 256){ sWL[i] = WL[p*4096 + i]; sWR[i] = WR[p*4096 + i]; }
    __syncthreads();
    float xv[8];
    #pragma unroll
    for (int i = 0; i < 8; ++i) xv[i] = (base + i < NN) ? X[p][(size_t)(base+i)*64 + lane] : 0.f;
    for (int k = 0; k < 64; ++k){
      float wl = sWL[k*64 + lane], wr = sWR[k*64 + lane];
      #pragma unroll
      for (int i = 0; i < 8; ++i){
        float xs = __shfl(xv[i], k);
        accY[i] = fmaf(xs, wl, accY[i]);
        accR[i] = fmaf(xs, wr, accR[i]);
      }
    }
  }
  float bias = vbl[lane];
  #pragma unroll
  for (int i = 0; i < 8; ++i){
    int n = base + i;
    if (n < NN){
      Y[(size_t)n*64 + lane] = accY[i];
      R[(size_t)n*64 + lane] = accR[i] + bias;
    }
  }
}

// v = relu(bn(Yagg + R)); mu = v@Wm + bm; lv = v@Wv + bv
__global__ void __launch_bounds__(256) k_mulv(const float* __restrict__ Yagg,
                                              const float* __restrict__ R,
                                              const float* __restrict__ g,
                                              const float* __restrict__ be,
                                              const float* __restrict__ m,
                                              const float* __restrict__ var_,
                                              const float* __restrict__ Wm,
                                              const float* __restrict__ bm,
                                              const float* __restrict__ Wv,
                                              const float* __restrict__ bv,
                                              float* __restrict__ mu, float* __restrict__ lv){
  __shared__ float sWm[4096], sWv[4096];
  __shared__ float sbm[64], sbv[64], ssc[64], ssh[64];
  for (int i = threadIdx.x; i < 4096; i += 256){ sWm[i] = Wm[i]; sWv[i] = Wv[i]; }
  if (threadIdx.x < 64){
    int f = threadIdx.x;
    float sc = g[f] * rsqrtf(var_[f] + EPS_BN);
    ssc[f] = sc; ssh[f] = be[f] - m[f] * sc;
    sbm[f] = bm[f]; sbv[f] = bv[f];
  }
  __syncthreads();
  int lane = threadIdx.x & 63, wib = threadIdx.x >> 6;
  int stride = (blockDim.x >> 6) * gridDim.x;
  for (int n = blockIdx.x * (blockDim.x >> 6) + wib; n < NN; n += stride){
    float t  = Yagg[(size_t)n*64 + lane] + R[(size_t)n*64 + lane];
    float vv = fmaxf(fmaf(t, ssc[lane], ssh[lane]), 0.f);
    float am = sbm[lane], al = sbv[lane];
    #pragma unroll
    for (int k = 0; k < 64; ++k){
      float s = __shfl(vv, k);
      am = fmaf(s, sWm[k*64 + lane], am);
      al = fmaf(s, sWv[k*64 + lane], al);
    }
    mu[(size_t)n*64 + lane] = am;
    lv[(size_t)n*64 + lane] = al;
  }
}

// rank = relu(mu@W1+b1) @ W2 + b2
__global__ void __launch_bounds__(256) k_rank(const float* __restrict__ mu,
                                              const float* __restrict__ W1,
                                              const float* __restrict__ b1,
                                              const float* __restrict__ W2,
                                              const float* __restrict__ b2,
                                              float* __restrict__ rout){
  __shared__ float sW[4096];
  __shared__ float sb1[64], sw2[64];
  for (int i = threadIdx.x; i < 4096; i += 256) sW[i] = W1[i];
  if (threadIdx.x < 64){ sb1[threadIdx.x] = b1[threadIdx.x]; sw2[threadIdx.x] = W2[threadIdx.x]; }
  __syncthreads();
  int lane = threadIdx.x & 63, wib = threadIdx.x >> 6;
  int stride = (blockDim.x >> 6) * gridDim.x;
  float b2v = b2[0];
  for (int n = blockIdx.x * (blockDim.x >> 6) + wib; n < NN; n += stride){
    float muv = mu[(size_t)n*64 + lane];
    float t = sb1[lane];
    #pragma unroll
    for (int k = 0; k < 64; ++k) t = fmaf(__shfl(muv, k), sW[k*64 + lane], t);
    t = fmaxf(t, 0.f);
    float val = t * sw2[lane];
    #pragma unroll
    for (int s = 32; s > 0; s >>= 1) val += __shfl_xor(val, s);
    if (lane == 0) rout[n] = val + b2v;
  }
}

// reg head: reg_in(385) -> 64 relu -> 32 relu -> 1
__global__ void __launch_bounds__(256) k_reg(
    const float* __restrict__ x0, const float* __restrict__ x1, const float* __restrict__ x2,
    const float* __restrict__ x3, const float* __restrict__ x4, const float* __restrict__ x5,
    const float* __restrict__ rank,
    const float* __restrict__ W1, const float* __restrict__ b1,
    const float* __restrict__ W2, const float* __restrict__ b2,
    const float* __restrict__ W3, const float* __restrict__ b3,
    float* __restrict__ preds){
  __shared__ float sW[4096];
  __shared__ float sW2[2048];
  __shared__ float sW3[32];
  const float* X[6] = {x0, x1, x2, x3, x4, x5};
  int lane = threadIdx.x & 63, wib = threadIdx.x >> 6;
  int base = blockIdx.x * 32 + wib * 8;
  for (int i = threadIdx.x; i < 2048; i += 256) sW2[i] = W2[i];
  if (threadIdx.x < 32) sW3[threadIdx.x] = W3[threadIdx.x];
  float acc[8] = {0,0,0,0,0,0,0,0};
  #pragma unroll
  for (int p = 0; p < 6; ++p){
    __syncthreads();
    for (int i = threadIdx.x; i < 4096; i += 256) sW[i] = W1[p*4096 + i];
    __syncthreads();
    float xv[8];
    #pragma unroll
    for (int i = 0; i < 8; ++i) xv[i] = (base + i < NN) ? X[p][(size_t)(base+i)*64 + lane] : 0.f;
    for (int k = 0; k < 64; ++k){
      float wv = sW[k*64 + lane];
      #pragma unroll
      for (int i = 0; i < 8; ++i) acc[i] = fmaf(__shfl(xv[i], k), wv, acc[i]);
    }
  }
  float w384 = W1[4096*6 + lane];   // row 384 (rank_score)
  float b1v = b1[lane];
  int j = lane & 31, half = lane >> 5;
  float b2v = b2[j];
  float b3v = b3[0];
  #pragma unroll
  for (int i = 0; i < 8; ++i){
    int n = base + i;
    if (n >= NN) continue;
    float a = fmaxf(acc[i] + b1v + rank[n] * w384, 0.f);  // h1 across lanes
    float part = 0.f;
    #pragma unroll
    for (int kk = 0; kk < 32; ++kk){
      int k = half * 32 + kk;
      part = fmaf(__shfl(a, k), sW2[k*32 + j], part);
    }
    part += __shfl_xor(part, 32);
    float h2 = fmaxf(part + b2v, 0.f);
    float val = (lane < 32) ? h2 * sW3[j] : 0.f;
    #pragma unroll
    for (int s = 32; s > 0; s >>= 1) val += __shfl_xor(val, s);
    if (lane == 0) preds[n] = val + b3v;
  }
}

// ---------------- launch ----------------

extern "C" void kernel_launch(void* const* d_in, const int* in_sizes, int n_in,
                              void* d_out, int out_size, void* d_ws, size_t ws_size,
                              hipStream_t stream){
  const float* x    = (const float*)d_in[0];
  const int*   eidx = (const int*)d_in[1];
  const int* row = eidx;
  const int* col = eidx + EE;
  const float* W_in = (const float*)d_in[2];
  const float* b_in = (const float*)d_in[3];
  const float* sWl  = (const float*)d_in[4];
  const float* sbl  = (const float*)d_in[5];
  const float* sWr  = (const float*)d_in[6];
  const float* bng  = (const float*)d_in[7];
  const float* bnb  = (const float*)d_in[8];
  const float* bnm  = (const float*)d_in[9];
  const float* bnv  = (const float*)d_in[10];
  const float* vWl  = (const float*)d_in[11];
  const float* vbl  = (const float*)d_in[12];
  const float* vWr  = (const float*)d_in[13];
  const float* vg   = (const float*)d_in[14];
  const float* vbe  = (const float*)d_in[15];
  const float* vm   = (const float*)d_in[16];
  const float* vvar = (const float*)d_in[17];
  const float* Wmu  = (const float*)d_in[18];
  const float* bmu  = (const float*)d_in[19];
  const float* Wlv  = (const float*)d_in[20];
  const float* blv  = (const float*)d_in[21];
  const float* rW1  = (const float*)d_in[22];
  const float* rb1  = (const float*)d_in[23];
  const float* rW2  = (const float*)d_in[24];
  const float* rb2  = (const float*)d_in[25];
  const float* gW1  = (const float*)d_in[26];
  const float* gb1  = (const float*)d_in[27];
  const float* gW2  = (const float*)d_in[28];
  const float* gb2  = (const float*)d_in[29];
  const float* gW3  = (const float*)d_in[30];
  const float* gb3  = (const float*)d_in[31];

  float* preds = (float*)d_out;
  float* rank  = preds + NN;
  float* mu    = rank + NN;
  float* lv    = mu + (size_t)NN * 64;

  char* w = (char*)d_ws;
  auto alloc = [&](size_t bytes) -> char* {
    char* p = w; w += (bytes + 255) & ~(size_t)255; return p;
  };
  int*   outdeg = (int*)alloc((size_t)NN * 4);
  int*   incnt  = (int*)alloc((size_t)NN * 4);
  int*   bsrc   = (int*)alloc((size_t)NN * CAP * 4);
  float* bnorm  = (float*)alloc((size_t)NN * CAP * 4);
  float* skip   = (float*)alloc((size_t)NN * 64 * 4);
  float* hl[4];
  for (int i = 0; i < 4; ++i) hl[i] = (float*)alloc((size_t)NN * 64 * 4);
  float* meanb  = (float*)alloc((size_t)NN * 64 * 4);
  float* pa     = (float*)alloc((size_t)NN * 64 * 4);
  float* pb     = (float*)alloc((size_t)NN * 64 * 4);
  float* Yb     = (float*)alloc((size_t)NN * 64 * 4);
  float* Rb     = (float*)alloc((size_t)NN * 64 * 4);

  hipMemsetAsync(outdeg, 0, (size_t)NN * 4, stream);
  hipMemsetAsync(incnt,  0, (size_t)NN * 4, stream);

  const int EB = (EE + 255) / 256;
  k_outdeg<<<EB, 256, 0, stream>>>(row, outdeg);
  k_fill  <<<EB, 256, 0, stream>>>(row, col, outdeg, incnt, bsrc, bnorm);

  k_gemm64<<<1024, 256, 0, stream>>>(x, W_in, b_in, skip);

  const int AGG_B = NN / 4;  // wave per node, 4 waves/block
  const float* hprev = x;
  for (int i = 0; i < 4; ++i){
    k_agg_mean<<<AGG_B, 256, 0, stream>>>(hprev, meanb, bsrc, incnt);
    k_sage<<<1024, 256, 0, stream>>>(hprev, meanb, sWl + i*4096, sbl + i*64, sWr + i*4096,
                                     bng + i*64, bnb + i*64, bnm + i*64, bnv + i*64, hl[i]);
    hprev = hl[i];
  }

  k_agg_path<<<AGG_B, 256, 0, stream>>>(hl[3], pa, bsrc, bnorm, incnt);
  k_agg_path<<<AGG_B, 256, 0, stream>>>(pa, pb, bsrc, bnorm, incnt);
  k_agg_path<<<AGG_B, 256, 0, stream>>>(pb, pa, bsrc, bnorm, incnt);
  k_agg_path<<<AGG_B, 256, 0, stream>>>(pa, pb, bsrc, bnorm, incnt);
  // path_out = pb

  const int NB32 = (NN + 31) / 32;
  k_gemm_YR<<<NB32, 256, 0, stream>>>(hl[0], hl[1], hl[2], hl[3], skip, pb,
                                      vWl, vWr, vbl, Yb, Rb);
  k_agg_mean<<<AGG_B, 256, 0, stream>>>(Yb, meanb, bsrc, incnt);   // agg(Y)/cnt
  k_mulv<<<1024, 256, 0, stream>>>(meanb, Rb, vg, vbe, vm, vvar,
                                   Wmu, bmu, Wlv, blv, mu, lv);
  k_rank<<<1024, 256, 0, stream>>>(mu, rW1, rb1, rW2, rb2, rank);
  k_reg<<<NB32, 256, 0, stream>>>(hl[0], hl[1], hl[2], hl[3], skip, mu, rank,
                                  gW1, gb1, gW2, gb2, gW3, gb3, preds);
}